// Round 5
// baseline (492.445 us; speedup 1.0000x reference)
//
#include <hip/hip_runtime.h>
#include <climits>

// ---------------------------------------------------------------------------
// GCN 2-layer + graclus pooling, frontier-restricted (~8.7k nodes).
// Single full-E pass (k_bkt) buckets edges by dst>>10 with packed src;
// k_degB then does degree + frontier-edge capture per bucket entirely in LDS
// (no per-edge device atomics, no second full-E scan).
//   k_bkt  : chunk edges -> LDS sort by bucket -> dump (src<<10|dl, w)
//            + frontier-src marking via LDS mark1 bitset
//   k_degB : per-bucket LDS reduce -> dinv; capture edges with dst in
//            frontier via wave-aggregated append; counts2 via LDS
//   k_h1   : fused [aggregate x over frontier CSR] + [@W1 + b1]
//   k_h2out: fused [aggregate h1 at 512 sel] + [@W2 + b2] + pairwise max
// ---------------------------------------------------------------------------

#define NF_CAP 40960
#define CHUNK 4096
#define MAXW 3200          // mark1 bitset words for N<=102400

__global__ void k_init(unsigned int* mark1w, unsigned char* mark2,
                       int* fidx, int* counts2, int* first, int* cnt,
                       int* gcur, int n, int nb) {
  int i = blockIdx.x * blockDim.x + threadIdx.x;
  if (i < n) { mark2[i] = 0; fidx[i] = -1; }
  if (i < MAXW) mark1w[i] = 0;
  if (i < NF_CAP) counts2[i] = 0;
  if (i < nb) first[i] = INT_MAX;
  if (i < 4) cnt[i] = 0;
  if (i < 128) gcur[i] = 0;
}

__global__ void k_first(const int* __restrict__ batch, int* first, int nc) {
  int c = blockIdx.x * blockDim.x + threadIdx.x;
  if (c >= nc) return;
  int b0 = batch[2 * c], b1 = batch[2 * c + 1];
  atomicMin(&first[min(b0, b1)], c);
}

__global__ void k_sel(const int* __restrict__ first, int* sel,
                      unsigned int* mark1w, unsigned char* mark2, int nb, int nc) {
  int t = blockIdx.x * blockDim.x + threadIdx.x;
  if (t >= 2 * nb) return;
  int f = first[t >> 1];
  f = min(f, nc - 1);            // JAX gather clamps (empty-graph case)
  int node = 2 * f + (t & 1);
  sel[t] = node;
  atomicOr(&mark1w[node >> 5], 1u << (node & 31));
  mark2[node] = 1;
}

// --- pass 1: bucket edges by dst>>10; LDS-sorted coalesced dump --------------
__global__ __launch_bounds__(256) void k_bkt(const int* __restrict__ src,
    const int* __restrict__ dst, const float* __restrict__ w,
    const unsigned int* __restrict__ mark1w, unsigned char* mark2,
    int* gcur, uint2* bktbuf, int cap, int e, int nwords) {
  __shared__ int scnt[128], sbase[128], sgb[128];
  __shared__ unsigned int sd[CHUNK];       // packed (src<<10)|dst_local
  __shared__ float sw[CHUNK];
  __shared__ unsigned char sbk[CHUNK];     // bucket id per slot
  __shared__ unsigned int sm1[MAXW];       // mark1 bitset (12.8 KB)
  int t = threadIdx.x;
  if (t < 128) scnt[t] = 0;
  for (int j = t; j < nwords; j += 256) sm1[j] = mark1w[j];
  __syncthreads();
  int i0 = blockIdx.x * CHUNK;
  int rd[16], rs[16];
  float rw[16];
#pragma unroll
  for (int k = 0; k < 16; ++k) {
    int i = i0 + t + k * 256;
    if (i < e) {
      int d = dst[i];
      int s = src[i];
      rd[k] = d; rs[k] = s; rw[k] = w[i];
      atomicAdd(&scnt[d >> 10], 1);
      if ((sm1[d >> 5] >> (d & 31)) & 1u) mark2[s] = 1;   // src of selected
    } else {
      rd[k] = -1;
    }
  }
  __syncthreads();
  // exclusive scan of scnt[0..127]
  if (t < 128) sbase[t] = scnt[t];
  __syncthreads();
  for (int off = 1; off < 128; off <<= 1) {
    int a = (t < 128 && t >= off) ? sbase[t - off] : 0;
    __syncthreads();
    if (t < 128) sbase[t] += a;
    __syncthreads();
  }
  if (t < 128) {
    int c = scnt[t];
    sbase[t] -= c;
    sgb[t] = c ? atomicAdd(&gcur[t], c) : 0;   // <=128 device atomics / block
  }
  __syncthreads();
  if (t < 128) scnt[t] = 0;
  __syncthreads();
#pragma unroll
  for (int k = 0; k < 16; ++k) {
    if (rd[k] >= 0) {
      int b = rd[k] >> 10;
      int pos = atomicAdd(&scnt[b], 1) + sbase[b];
      sd[pos] = ((unsigned int)rs[k] << 10) | (unsigned int)(rd[k] & 1023);
      sw[pos] = rw[k];
      sbk[pos] = (unsigned char)b;
    }
  }
  __syncthreads();
  int tot = min(CHUNK, e - i0);
  for (int j = t; j < tot; j += 256) {
    int b = sbk[j];
    int gi = b * cap + sgb[b] + (j - sbase[b]);
    bktbuf[gi] = make_uint2(sd[j], __float_as_uint(sw[j]));
  }
}

__global__ void k_compact(const unsigned char* __restrict__ mark2, int* list,
                          int* fidx, int* cntF, int n) {
  int i = blockIdx.x * blockDim.x + threadIdx.x;
  if (i < n && mark2[i]) {
    int p = atomicAdd(cntF, 1);
    if (p < NF_CAP) { list[p] = i; fidx[i] = p; }
  }
}

// --- pass 2: per-bucket degree + frontier-edge capture (LDS only) ------------
__global__ __launch_bounds__(1024) void k_degB(const int* __restrict__ gcur,
    const uint2* __restrict__ bktbuf, int cap, const int* __restrict__ fidx,
    float* dinv, int* counts2, int* cntE,
    int* e_src, int* e_f, float* e_w, int n) {
  __shared__ float acc[1024];
  __shared__ int sfidx[1024];
  __shared__ int scount[1024];
  int t = threadIdx.x, b = blockIdx.x;
  int gbase = b << 10;
  acc[t] = 0.f;
  scount[t] = 0;
  sfidx[t] = (gbase + t < n) ? fidx[gbase + t] : -1;
  __syncthreads();
  int lane = t & 63;
  int m = min(gcur[b], cap);
  const uint2* base = bktbuf + (size_t)b * cap;
  for (int j0 = 0; j0 < m; j0 += 1024) {
    int j = j0 + t;
    int dl = 0, s = 0, f = -1;
    float wv = 0.f;
    if (j < m) {
      uint2 u = base[j];
      dl = (int)(u.x & 1023u);
      s = (int)(u.x >> 10);
      wv = __uint_as_float(u.y);
      atomicAdd(&acc[dl], wv);             // LDS fp32 atomic
      f = sfidx[dl];
    }
    bool matched = (f >= 0);
    if (matched) atomicAdd(&scount[dl], 1);
    unsigned long long mask = __ballot(matched);
    if (mask) {
      int leader = __ffsll(mask) - 1;
      int cnt = __popcll(mask);
      int gb = 0;
      if (lane == leader) gb = atomicAdd(cntE, cnt);   // 1 atomic / wave
      gb = __shfl(gb, leader);
      if (matched) {
        int r = gb + __popcll(mask & ((1ull << lane) - 1ull));
        e_src[r] = s; e_f[r] = f; e_w[r] = wv;
      }
    }
  }
  __syncthreads();
  int i = gbase + t;
  if (i < n) {
    dinv[i] = rsqrtf(1.0f + acc[t]);       // +1 = self-loop
    int f = sfidx[t];
    if (f >= 0) counts2[f] = scount[t];    // exclusive owner: no atomics
  }
}

// --- exclusive scan over frontier counts (single block) ----------------------
__global__ __launch_bounds__(1024) void k_scanF(const int* __restrict__ counts2,
                                                const int* __restrict__ cntF,
                                                const int* __restrict__ cntE,
                                                int* frowptr, int* fcursor) {
  __shared__ int sd[1024];
  __shared__ int carry;
  int t = threadIdx.x;
  int nf = min(*cntF, NF_CAP);
  if (t == 0) carry = 0;
  __syncthreads();
  for (int base = 0; base < nf; base += 1024) {
    int i = base + t;
    int v = (i < nf) ? counts2[i] : 0;
    sd[t] = v; __syncthreads();
    for (int off = 1; off < 1024; off <<= 1) {
      int a = (t >= off) ? sd[t - off] : 0;
      __syncthreads();
      sd[t] += a;
      __syncthreads();
    }
    int c = carry;
    if (i < nf) { int r = c + sd[t] - v; frowptr[i] = r; fcursor[i] = r; }
    __syncthreads();
    if (t == 1023) carry = c + sd[t];
    __syncthreads();
  }
  if (t == 0) frowptr[nf] = *cntE;
}

__global__ void k_scatF(const int* __restrict__ e_src, const int* __restrict__ e_f,
                        const float* __restrict__ e_w, const int* __restrict__ cntE,
                        const float* __restrict__ dinv,
                        int* fcursor, int* fcols, float* fvals) {
  int m = *cntE;
  int stride = gridDim.x * blockDim.x;
  for (int i = blockIdx.x * blockDim.x + threadIdx.x; i < m; i += stride) {
    int f = e_f[i], s = e_src[i];
    int p = atomicAdd(&fcursor[f], 1);
    fcols[p] = s;
    fvals[p] = dinv[s] * e_w[i];           // dst-side dinv applied in k_h1
  }
}

// --- fused: aggregate x over frontier CSR, then @W1 + b1 ---------------------
__global__ __launch_bounds__(256) void k_h1(const float* __restrict__ x,
    const int* __restrict__ list, const int* __restrict__ cntF,
    const int* __restrict__ frowptr, const int* __restrict__ fcols,
    const float* __restrict__ fvals, const float* __restrict__ dinv,
    const float* __restrict__ W1, const float* __restrict__ b1,
    float* __restrict__ h1) {
  __shared__ float Wl[128 * 64];           // 32 KB
  __shared__ float sag[4][130];
  int t = threadIdx.x;
  for (int p = t; p < 128 * 16; p += 256)
    ((float4*)Wl)[p] = ((const float4*)W1)[p];
  __syncthreads();
  int lane = t & 63, wv = t >> 6;
  int wid = blockIdx.x * 4 + wv;
  int nw = gridDim.x * 4;
  int m = min(*cntF, NF_CAP);
  const float2* x2 = (const float2*)x;
  float bias = b1[lane];
  for (int li = wid; li < m; li += nw) {
    int i = list[li];
    float dv = dinv[i];
    float2 xi = x2[(size_t)i * 64 + lane];
    float2 acc = {0.f, 0.f};
    int beg = frowptr[li], end = frowptr[li + 1];
    for (int p = beg; p < end; ++p) {
      int c = fcols[p];
      float v = fvals[p];
      float2 xc = x2[(size_t)c * 64 + lane];
      acc.x += v * xc.x;
      acc.y += v * xc.y;
    }
    acc.x = dv * (acc.x + dv * xi.x);
    acc.y = dv * (acc.y + dv * xi.y);
    sag[wv][2 * lane] = acc.x;
    sag[wv][2 * lane + 1] = acc.y;
    asm volatile("s_waitcnt lgkmcnt(0)" ::: "memory");
    float o = bias;
#pragma unroll 8
    for (int k = 0; k < 128; ++k)
      o += sag[wv][k] * Wl[k * 64 + lane];
    h1[(size_t)li * 64 + lane] = o;
  }
}

// --- fused: aggregate h1 at 512 sel nodes, @W2 + b2, pairwise max, out -------
__global__ __launch_bounds__(128) void k_h2out(const float* __restrict__ h1,
    const int* __restrict__ sel, const int* __restrict__ fidx,
    const int* __restrict__ frowptr, const int* __restrict__ fcols,
    const float* __restrict__ fvals, const float* __restrict__ dinv,
    const float* __restrict__ W2, const float* __restrict__ b2,
    float* __restrict__ out, int nb) {
  __shared__ float Wl[64 * 64];
  __shared__ float sag[2][64];
  __shared__ float hh[2][64];
  int t = threadIdx.x;
  for (int p = t; p < 64 * 16; p += 128)
    ((float4*)Wl)[p] = ((const float4*)W2)[p];
  __syncthreads();
  int lane = t & 63, wv = t >> 6;
  int b = blockIdx.x;
  if (b >= nb) return;
  int node = sel[2 * b + wv];
  int f = fidx[node];
  float dv = dinv[node];
  float acc = 0.f;
  int beg = frowptr[f], end = frowptr[f + 1];
  for (int p = beg; p < end; ++p) {
    int g = fidx[fcols[p]];
    acc += fvals[p] * h1[(size_t)g * 64 + lane];
  }
  acc = dv * (acc + dv * h1[(size_t)f * 64 + lane]);
  sag[wv][lane] = acc;
  __syncthreads();
  float o = b2[lane];
#pragma unroll 8
  for (int k = 0; k < 64; ++k)
    o += sag[wv][k] * Wl[k * 64 + lane];
  hh[wv][lane] = o;
  __syncthreads();
  if (wv == 0)
    out[(size_t)b * 64 + lane] = fmaxf(hh[0][lane], hh[1][lane]);
}

extern "C" void kernel_launch(void* const* d_in, const int* in_sizes, int n_in,
                              void* d_out, int out_size, void* d_ws, size_t ws_size,
                              hipStream_t stream) {
  const float* x     = (const float*)d_in[0];
  const int*   ei    = (const int*)d_in[1];
  const float* ew    = (const float*)d_in[2];
  const int*   batch = (const int*)d_in[3];
  const float* W1    = (const float*)d_in[4];
  const float* b1    = (const float*)d_in[5];
  const float* W2    = (const float*)d_in[6];
  const float* b2    = (const float*)d_in[7];

  const int E  = in_sizes[2];
  const int N  = in_sizes[3];
  const int B  = out_size / 64;
  const int NC = N / 2;
  const int* srcI = ei;
  const int* dstI = ei + E;

  const int NBKT   = (N + 1023) >> 10;              // 98 for N=100k
  const int CAP    = ((E + NBKT - 1) / NBKT) * 2;   // ~2x expected bucket load
  const int NWORDS = (N + 31) >> 5;

  char* p = (char*)d_ws;
  auto alloc = [&](size_t bytes) -> char* {
    char* r = p;
    p += (bytes + 255) & ~size_t(255);
    return r;
  };
  float* dinv    = (float*)alloc((size_t)N * 4);
  unsigned int* mark1w = (unsigned int*)alloc((size_t)MAXW * 4);
  unsigned char* mark2 = (unsigned char*)alloc(N);
  int*   fidx    = (int*)alloc((size_t)N * 4);
  int*   list    = (int*)alloc((size_t)NF_CAP * 4);
  int*   counts2 = (int*)alloc((size_t)NF_CAP * 4);
  int*   frowptr = (int*)alloc((size_t)(NF_CAP + 1) * 4);
  int*   fcursor = (int*)alloc((size_t)NF_CAP * 4);
  int*   first   = (int*)alloc((size_t)B * 4);
  int*   sel     = (int*)alloc((size_t)2 * B * 4);
  int*   cnt     = (int*)alloc(256);                // [0]=cntF, [1]=cntE
  int*   gcur    = (int*)alloc(128 * 4);
  uint2* bktbuf  = (uint2*)alloc((size_t)NBKT * CAP * 8);
  int*   e_src   = (int*)alloc((size_t)E * 4);
  int*   e_f     = (int*)alloc((size_t)E * 4);
  float* e_w     = (float*)alloc((size_t)E * 4);
  int*   fcols   = (int*)alloc((size_t)E * 4);
  float* fvals   = (float*)alloc((size_t)E * 4);
  float* h1      = (float*)alloc((size_t)NF_CAP * 64 * 4);

  int gN = (N + 255) / 256;
  int gB = (E + CHUNK - 1) / CHUNK;
  int* cntF = cnt;
  int* cntE = cnt + 1;

  k_init<<<gN, 256, 0, stream>>>(mark1w, mark2, fidx, counts2, first, cnt, gcur, N, B);
  k_first<<<(NC + 255) / 256, 256, 0, stream>>>(batch, first, NC);
  k_sel<<<(2 * B + 255) / 256, 256, 0, stream>>>(first, sel, mark1w, mark2, B, NC);
  k_bkt<<<gB, 256, 0, stream>>>(srcI, dstI, ew, mark1w, mark2, gcur, bktbuf, CAP, E, NWORDS);
  k_compact<<<gN, 256, 0, stream>>>(mark2, list, fidx, cntF, N);
  k_degB<<<NBKT, 1024, 0, stream>>>(gcur, bktbuf, CAP, fidx, dinv, counts2, cntE,
                                    e_src, e_f, e_w, N);
  k_scanF<<<1, 1024, 0, stream>>>(counts2, cntF, cntE, frowptr, fcursor);
  k_scatF<<<256, 256, 0, stream>>>(e_src, e_f, e_w, cntE, dinv, fcursor, fcols, fvals);
  k_h1<<<1024, 256, 0, stream>>>(x, list, cntF, frowptr, fcols, fvals, dinv, W1, b1, h1);
  k_h2out<<<B, 128, 0, stream>>>(h1, sel, fidx, frowptr, fcols, fvals, dinv, W2, b2,
                                 (float*)d_out, B);
}

// Round 6
// 229.055 us; speedup vs baseline: 2.1499x; 2.1499x over previous
//
#include <hip/hip_runtime.h>
#include <climits>

// ---------------------------------------------------------------------------
// GCN 2-layer + graclus pooling, frontier-restricted (~8.7k nodes).
// Single full-E pass (k_bkt) buckets edges by dst>>10 (packed src|dst_local).
// Per-bucket kernels then work entirely in LDS (no per-edge device atomics,
// no global cursors):
//   k_bkt  : chunk edges -> LDS sort by bucket -> dump (src<<10|dl, w)
//            + frontier-src marking via LDS mark1 bitset
//   k_degB : per-bucket LDS degree reduce -> dinv; per-node match counts2
//   k_scanF: scan counts2 -> frowptr
//   k_scat2: re-stream bucket; matched edges -> fcols/fvals via LDS cursors
//   k_h1   : fused [aggregate x over frontier CSR] + [@W1 + b1]
//   k_h2out: fused [aggregate h1 at 512 sel] + [@W2 + b2] + pairwise max
// ---------------------------------------------------------------------------

#define NF_CAP 40960
#define CHUNK 4096
#define MAXW 3200          // mark1 bitset words for N<=102400

__global__ void k_init(unsigned int* mark1w, unsigned char* mark2,
                       int* fidx, int* counts2, int* first, int* cnt,
                       int* gcur, int n, int nb) {
  int i = blockIdx.x * blockDim.x + threadIdx.x;
  if (i < n) { mark2[i] = 0; fidx[i] = -1; }
  if (i < MAXW) mark1w[i] = 0;
  if (i < NF_CAP) counts2[i] = 0;
  if (i < nb) first[i] = INT_MAX;
  if (i < 4) cnt[i] = 0;
  if (i < 128) gcur[i] = 0;
}

__global__ void k_first(const int* __restrict__ batch, int* first, int nc) {
  int c = blockIdx.x * blockDim.x + threadIdx.x;
  if (c >= nc) return;
  int b0 = batch[2 * c], b1 = batch[2 * c + 1];
  atomicMin(&first[min(b0, b1)], c);
}

__global__ void k_sel(const int* __restrict__ first, int* sel,
                      unsigned int* mark1w, unsigned char* mark2, int nb, int nc) {
  int t = blockIdx.x * blockDim.x + threadIdx.x;
  if (t >= 2 * nb) return;
  int f = first[t >> 1];
  f = min(f, nc - 1);            // JAX gather clamps (empty-graph case)
  int node = 2 * f + (t & 1);
  sel[t] = node;
  atomicOr(&mark1w[node >> 5], 1u << (node & 31));
  mark2[node] = 1;
}

// --- pass 1: bucket edges by dst>>10; LDS-sorted coalesced dump --------------
__global__ __launch_bounds__(256) void k_bkt(const int* __restrict__ src,
    const int* __restrict__ dst, const float* __restrict__ w,
    const unsigned int* __restrict__ mark1w, unsigned char* mark2,
    int* gcur, uint2* bktbuf, int cap, int e, int nwords) {
  __shared__ int scnt[128], sbase[128], sgb[128];
  __shared__ unsigned int sd[CHUNK];       // packed (src<<10)|dst_local
  __shared__ float sw[CHUNK];
  __shared__ unsigned char sbk[CHUNK];     // bucket id per slot
  __shared__ unsigned int sm1[MAXW];       // mark1 bitset (12.8 KB)
  int t = threadIdx.x;
  if (t < 128) scnt[t] = 0;
  for (int j = t; j < nwords; j += 256) sm1[j] = mark1w[j];
  __syncthreads();
  int i0 = blockIdx.x * CHUNK;
  int rd[16], rs[16];
  float rw[16];
#pragma unroll
  for (int k = 0; k < 16; ++k) {
    int i = i0 + t + k * 256;
    if (i < e) {
      int d = dst[i];
      int s = src[i];
      rd[k] = d; rs[k] = s; rw[k] = w[i];
      atomicAdd(&scnt[d >> 10], 1);
      if ((sm1[d >> 5] >> (d & 31)) & 1u) mark2[s] = 1;   // src of selected
    } else {
      rd[k] = -1;
    }
  }
  __syncthreads();
  // exclusive scan of scnt[0..127]
  if (t < 128) sbase[t] = scnt[t];
  __syncthreads();
  for (int off = 1; off < 128; off <<= 1) {
    int a = (t < 128 && t >= off) ? sbase[t - off] : 0;
    __syncthreads();
    if (t < 128) sbase[t] += a;
    __syncthreads();
  }
  if (t < 128) {
    int c = scnt[t];
    sbase[t] -= c;
    sgb[t] = c ? atomicAdd(&gcur[t], c) : 0;   // <=128 device atomics / block
  }
  __syncthreads();
  if (t < 128) scnt[t] = 0;
  __syncthreads();
#pragma unroll
  for (int k = 0; k < 16; ++k) {
    if (rd[k] >= 0) {
      int b = rd[k] >> 10;
      int pos = atomicAdd(&scnt[b], 1) + sbase[b];
      sd[pos] = ((unsigned int)rs[k] << 10) | (unsigned int)(rd[k] & 1023);
      sw[pos] = rw[k];
      sbk[pos] = (unsigned char)b;
    }
  }
  __syncthreads();
  int tot = min(CHUNK, e - i0);
  for (int j = t; j < tot; j += 256) {
    int b = sbk[j];
    int gi = b * cap + sgb[b] + (j - sbase[b]);
    bktbuf[gi] = make_uint2(sd[j], __float_as_uint(sw[j]));
  }
}

__global__ void k_compact(const unsigned char* __restrict__ mark2, int* list,
                          int* fidx, int* cntF, int n) {
  int i = blockIdx.x * blockDim.x + threadIdx.x;
  if (i < n && mark2[i]) {
    int p = atomicAdd(cntF, 1);
    if (p < NF_CAP) { list[p] = i; fidx[i] = p; }
  }
}

// --- pass 2a: per-bucket degree + per-node frontier match counts (LDS) -------
__global__ __launch_bounds__(1024) void k_degB(const int* __restrict__ gcur,
    const uint2* __restrict__ bktbuf, int cap, const int* __restrict__ fidx,
    float* dinv, int* counts2, int n) {
  __shared__ float acc[1024];
  __shared__ int sfidx[1024];
  __shared__ int scount[1024];
  int t = threadIdx.x, b = blockIdx.x;
  int gbase = b << 10;
  acc[t] = 0.f;
  scount[t] = 0;
  sfidx[t] = (gbase + t < n) ? fidx[gbase + t] : -1;
  __syncthreads();
  int m = min(gcur[b], cap);
  const uint2* base = bktbuf + (size_t)b * cap;
  for (int j = t; j < m; j += 1024) {
    uint2 u = base[j];
    int dl = (int)(u.x & 1023u);
    atomicAdd(&acc[dl], __uint_as_float(u.y));    // LDS fp32 atomic
    if (sfidx[dl] >= 0) atomicAdd(&scount[dl], 1);
  }
  __syncthreads();
  int i = gbase + t;
  if (i < n) {
    dinv[i] = rsqrtf(1.0f + acc[t]);              // +1 = self-loop
    int f = sfidx[t];
    if (f >= 0) counts2[f] = scount[t];           // exclusive owner: no atomic
  }
}

// --- exclusive scan over frontier counts (single block) ----------------------
__global__ __launch_bounds__(1024) void k_scanF(const int* __restrict__ counts2,
                                                const int* __restrict__ cntF,
                                                int* frowptr) {
  __shared__ int sd[1024];
  __shared__ int carry;
  int t = threadIdx.x;
  int nf = min(*cntF, NF_CAP);
  if (t == 0) carry = 0;
  __syncthreads();
  for (int base = 0; base < nf; base += 1024) {
    int i = base + t;
    int v = (i < nf) ? counts2[i] : 0;
    sd[t] = v; __syncthreads();
    for (int off = 1; off < 1024; off <<= 1) {
      int a = (t >= off) ? sd[t - off] : 0;
      __syncthreads();
      sd[t] += a;
      __syncthreads();
    }
    int c = carry;
    if (i < nf) frowptr[i] = c + sd[t] - v;
    __syncthreads();
    if (t == 1023) carry = c + sd[t];
    __syncthreads();
  }
  if (t == 0) frowptr[nf] = carry;
}

// --- pass 2b: scatter matched edges straight into frontier CSR ---------------
__global__ __launch_bounds__(1024) void k_scat2(const int* __restrict__ gcur,
    const uint2* __restrict__ bktbuf, int cap, const int* __restrict__ fidx,
    const int* __restrict__ frowptr, const float* __restrict__ dinv,
    int* fcols, float* fvals, int n) {
  __shared__ int sfidx[1024];
  __shared__ int lcur[1024];
  int t = threadIdx.x, b = blockIdx.x;
  int gbase = b << 10;
  int f = (gbase + t < n) ? fidx[gbase + t] : -1;
  sfidx[t] = f;
  lcur[t] = (f >= 0) ? frowptr[f] : 0;
  __syncthreads();
  int m = min(gcur[b], cap);
  const uint2* base = bktbuf + (size_t)b * cap;
  for (int j = t; j < m; j += 1024) {
    uint2 u = base[j];
    int dl = (int)(u.x & 1023u);
    if (sfidx[dl] >= 0) {
      int pos = atomicAdd(&lcur[dl], 1);          // LDS cursor, no global atomics
      int s = (int)(u.x >> 10);
      fcols[pos] = s;
      fvals[pos] = dinv[s] * __uint_as_float(u.y);   // dst-side dinv in k_h1
    }
  }
}

// --- fused: aggregate x over frontier CSR, then @W1 + b1 ---------------------
__global__ __launch_bounds__(256) void k_h1(const float* __restrict__ x,
    const int* __restrict__ list, const int* __restrict__ cntF,
    const int* __restrict__ frowptr, const int* __restrict__ fcols,
    const float* __restrict__ fvals, const float* __restrict__ dinv,
    const float* __restrict__ W1, const float* __restrict__ b1,
    float* __restrict__ h1) {
  __shared__ float Wl[128 * 64];           // 32 KB
  __shared__ float sag[4][130];
  int t = threadIdx.x;
  for (int p = t; p < 128 * 16; p += 256)
    ((float4*)Wl)[p] = ((const float4*)W1)[p];
  __syncthreads();
  int lane = t & 63, wv = t >> 6;
  int wid = blockIdx.x * 4 + wv;
  int nw = gridDim.x * 4;
  int m = min(*cntF, NF_CAP);
  const float2* x2 = (const float2*)x;
  float bias = b1[lane];
  for (int li = wid; li < m; li += nw) {
    int i = list[li];
    float dv = dinv[i];
    float2 xi = x2[(size_t)i * 64 + lane];
    float2 acc = {0.f, 0.f};
    int beg = frowptr[li], end = frowptr[li + 1];
    for (int p = beg; p < end; ++p) {
      int c = fcols[p];
      float v = fvals[p];
      float2 xc = x2[(size_t)c * 64 + lane];
      acc.x += v * xc.x;
      acc.y += v * xc.y;
    }
    acc.x = dv * (acc.x + dv * xi.x);
    acc.y = dv * (acc.y + dv * xi.y);
    sag[wv][2 * lane] = acc.x;
    sag[wv][2 * lane + 1] = acc.y;
    asm volatile("s_waitcnt lgkmcnt(0)" ::: "memory");
    float o = bias;
#pragma unroll 8
    for (int k = 0; k < 128; ++k)
      o += sag[wv][k] * Wl[k * 64 + lane];
    h1[(size_t)li * 64 + lane] = o;
  }
}

// --- fused: aggregate h1 at 512 sel nodes, @W2 + b2, pairwise max, out -------
__global__ __launch_bounds__(128) void k_h2out(const float* __restrict__ h1,
    const int* __restrict__ sel, const int* __restrict__ fidx,
    const int* __restrict__ frowptr, const int* __restrict__ fcols,
    const float* __restrict__ fvals, const float* __restrict__ dinv,
    const float* __restrict__ W2, const float* __restrict__ b2,
    float* __restrict__ out, int nb) {
  __shared__ float Wl[64 * 64];
  __shared__ float sag[2][64];
  __shared__ float hh[2][64];
  int t = threadIdx.x;
  for (int p = t; p < 64 * 16; p += 128)
    ((float4*)Wl)[p] = ((const float4*)W2)[p];
  __syncthreads();
  int lane = t & 63, wv = t >> 6;
  int b = blockIdx.x;
  if (b >= nb) return;
  int node = sel[2 * b + wv];
  int f = fidx[node];
  float dv = dinv[node];
  float acc = 0.f;
  int beg = frowptr[f], end = frowptr[f + 1];
  for (int p = beg; p < end; ++p) {
    int g = fidx[fcols[p]];
    acc += fvals[p] * h1[(size_t)g * 64 + lane];
  }
  acc = dv * (acc + dv * h1[(size_t)f * 64 + lane]);
  sag[wv][lane] = acc;
  __syncthreads();
  float o = b2[lane];
#pragma unroll 8
  for (int k = 0; k < 64; ++k)
    o += sag[wv][k] * Wl[k * 64 + lane];
  hh[wv][lane] = o;
  __syncthreads();
  if (wv == 0)
    out[(size_t)b * 64 + lane] = fmaxf(hh[0][lane], hh[1][lane]);
}

extern "C" void kernel_launch(void* const* d_in, const int* in_sizes, int n_in,
                              void* d_out, int out_size, void* d_ws, size_t ws_size,
                              hipStream_t stream) {
  const float* x     = (const float*)d_in[0];
  const int*   ei    = (const int*)d_in[1];
  const float* ew    = (const float*)d_in[2];
  const int*   batch = (const int*)d_in[3];
  const float* W1    = (const float*)d_in[4];
  const float* b1    = (const float*)d_in[5];
  const float* W2    = (const float*)d_in[6];
  const float* b2    = (const float*)d_in[7];

  const int E  = in_sizes[2];
  const int N  = in_sizes[3];
  const int B  = out_size / 64;
  const int NC = N / 2;
  const int* srcI = ei;
  const int* dstI = ei + E;

  const int NBKT   = (N + 1023) >> 10;              // 98 for N=100k
  const int CAP    = ((E + NBKT - 1) / NBKT) * 2;   // ~2x expected bucket load
  const int NWORDS = (N + 31) >> 5;

  char* p = (char*)d_ws;
  auto alloc = [&](size_t bytes) -> char* {
    char* r = p;
    p += (bytes + 255) & ~size_t(255);
    return r;
  };
  float* dinv    = (float*)alloc((size_t)N * 4);
  unsigned int* mark1w = (unsigned int*)alloc((size_t)MAXW * 4);
  unsigned char* mark2 = (unsigned char*)alloc(N);
  int*   fidx    = (int*)alloc((size_t)N * 4);
  int*   list    = (int*)alloc((size_t)NF_CAP * 4);
  int*   counts2 = (int*)alloc((size_t)NF_CAP * 4);
  int*   frowptr = (int*)alloc((size_t)(NF_CAP + 1) * 4);
  int*   first   = (int*)alloc((size_t)B * 4);
  int*   sel     = (int*)alloc((size_t)2 * B * 4);
  int*   cnt     = (int*)alloc(256);                // [0]=cntF
  int*   gcur    = (int*)alloc(128 * 4);
  uint2* bktbuf  = (uint2*)alloc((size_t)NBKT * CAP * 8);
  int*   fcols   = (int*)alloc((size_t)E * 4);
  float* fvals   = (float*)alloc((size_t)E * 4);
  float* h1      = (float*)alloc((size_t)NF_CAP * 64 * 4);

  int gN = (N + 255) / 256;
  int gB = (E + CHUNK - 1) / CHUNK;
  int* cntF = cnt;

  k_init<<<gN, 256, 0, stream>>>(mark1w, mark2, fidx, counts2, first, cnt, gcur, N, B);
  k_first<<<(NC + 255) / 256, 256, 0, stream>>>(batch, first, NC);
  k_sel<<<(2 * B + 255) / 256, 256, 0, stream>>>(first, sel, mark1w, mark2, B, NC);
  k_bkt<<<gB, 256, 0, stream>>>(srcI, dstI, ew, mark1w, mark2, gcur, bktbuf, CAP, E, NWORDS);
  k_compact<<<gN, 256, 0, stream>>>(mark2, list, fidx, cntF, N);
  k_degB<<<NBKT, 1024, 0, stream>>>(gcur, bktbuf, CAP, fidx, dinv, counts2, N);
  k_scanF<<<1, 1024, 0, stream>>>(counts2, cntF, frowptr);
  k_scat2<<<NBKT, 1024, 0, stream>>>(gcur, bktbuf, CAP, fidx, frowptr, dinv, fcols, fvals, N);
  k_h1<<<1024, 256, 0, stream>>>(x, list, cntF, frowptr, fcols, fvals, dinv, W1, b1, h1);
  k_h2out<<<B, 128, 0, stream>>>(h1, sel, fidx, frowptr, fcols, fvals, dinv, W2, b2,
                                 (float*)d_out, B);
}

// Round 7
// 170.155 us; speedup vs baseline: 2.8941x; 1.3462x over previous
//
#include <hip/hip_runtime.h>
#include <climits>

// ---------------------------------------------------------------------------
// GCN 2-layer + graclus pooling, frontier-restricted (~8.7k nodes).
// Single full-E pass (k_bkt) buckets edges by dst>>10 (packed src|dst_local).
// Per-bucket kernels then work entirely in LDS (no per-edge device atomics,
// no global cursors):
//   k_first: boundary-detect first cluster per graph (batch is SORTED -> no atomics)
//   k_bkt  : chunk edges -> LDS sort by bucket -> dump (src<<10|dl, w)
//            + frontier-src marking via LDS mark1 bitset
//   k_degB : per-bucket LDS degree reduce -> dinv; per-node match counts2
//   k_scanF: scan counts2 -> frowptr
//   k_scat2: re-stream bucket; matched edges -> fcols/fvals via LDS cursors
//   k_h1   : fused [aggregate x over frontier CSR] + [@W1 + b1]
//   k_h2out: fused [aggregate h1 at 512 sel] + [@W2 + b2] + pairwise max
// ---------------------------------------------------------------------------

#define NF_CAP 40960
#define CHUNK 4096
#define MAXW 3200          // mark1 bitset words for N<=102400

__global__ void k_init(unsigned int* mark1w, unsigned char* mark2,
                       int* fidx, int* counts2, int* first, int* cnt,
                       int* gcur, int n, int nb) {
  int i = blockIdx.x * blockDim.x + threadIdx.x;
  if (i < n) { mark2[i] = 0; fidx[i] = -1; }
  if (i < MAXW) mark1w[i] = 0;
  if (i < NF_CAP) counts2[i] = 0;
  if (i < nb) first[i] = INT_MAX;
  if (i < 4) cnt[i] = 0;
  if (i < 128) gcur[i] = 0;
}

// batch is sorted => bp[c]=batch[2c] is non-decreasing; first[b] = boundary c.
__global__ void k_first(const int* __restrict__ batch, int* first, int nc) {
  int c = blockIdx.x * blockDim.x + threadIdx.x;
  if (c >= nc) return;
  int b = batch[2 * c];
  if (c == 0 || batch[2 * c - 2] != b) first[b] = c;
}

__global__ void k_sel(const int* __restrict__ first, int* sel,
                      unsigned int* mark1w, unsigned char* mark2, int nb, int nc) {
  int t = blockIdx.x * blockDim.x + threadIdx.x;
  if (t >= 2 * nb) return;
  int f = first[t >> 1];
  f = min(f, nc - 1);            // JAX gather clamps (empty-graph case)
  int node = 2 * f + (t & 1);
  sel[t] = node;
  atomicOr(&mark1w[node >> 5], 1u << (node & 31));
  mark2[node] = 1;
}

// --- pass 1: bucket edges by dst>>10; LDS-sorted coalesced dump --------------
__global__ __launch_bounds__(256) void k_bkt(const int* __restrict__ src,
    const int* __restrict__ dst, const float* __restrict__ w,
    const unsigned int* __restrict__ mark1w, unsigned char* mark2,
    int* gcur, uint2* bktbuf, int cap, int e, int nwords) {
  __shared__ int scnt[128], sbase[128], sgb[128];
  __shared__ unsigned int sd[CHUNK];       // packed (src<<10)|dst_local
  __shared__ float sw[CHUNK];
  __shared__ unsigned char sbk[CHUNK];     // bucket id per slot
  __shared__ unsigned int sm1[MAXW];       // mark1 bitset (12.8 KB)
  int t = threadIdx.x;
  if (t < 128) scnt[t] = 0;
  for (int j = t; j < nwords; j += 256) sm1[j] = mark1w[j];
  __syncthreads();
  int i0 = blockIdx.x * CHUNK;
  int rd[16], rs[16];
  float rw[16];
#pragma unroll
  for (int k = 0; k < 16; ++k) {
    int i = i0 + t + k * 256;
    if (i < e) {
      int d = dst[i];
      int s = src[i];
      rd[k] = d; rs[k] = s; rw[k] = w[i];
      atomicAdd(&scnt[d >> 10], 1);
      if ((sm1[d >> 5] >> (d & 31)) & 1u) mark2[s] = 1;   // src of selected
    } else {
      rd[k] = -1;
    }
  }
  __syncthreads();
  // exclusive scan of scnt[0..127]
  if (t < 128) sbase[t] = scnt[t];
  __syncthreads();
  for (int off = 1; off < 128; off <<= 1) {
    int a = (t < 128 && t >= off) ? sbase[t - off] : 0;
    __syncthreads();
    if (t < 128) sbase[t] += a;
    __syncthreads();
  }
  if (t < 128) {
    int c = scnt[t];
    sbase[t] -= c;
    sgb[t] = c ? atomicAdd(&gcur[t], c) : 0;   // <=128 device atomics / block
  }
  __syncthreads();
  if (t < 128) scnt[t] = 0;
  __syncthreads();
#pragma unroll
  for (int k = 0; k < 16; ++k) {
    if (rd[k] >= 0) {
      int b = rd[k] >> 10;
      int pos = atomicAdd(&scnt[b], 1) + sbase[b];
      sd[pos] = ((unsigned int)rs[k] << 10) | (unsigned int)(rd[k] & 1023);
      sw[pos] = rw[k];
      sbk[pos] = (unsigned char)b;
    }
  }
  __syncthreads();
  int tot = min(CHUNK, e - i0);
  for (int j = t; j < tot; j += 256) {
    int b = sbk[j];
    int gi = b * cap + sgb[b] + (j - sbase[b]);
    bktbuf[gi] = make_uint2(sd[j], __float_as_uint(sw[j]));
  }
}

__global__ void k_compact(const unsigned char* __restrict__ mark2, int* list,
                          int* fidx, int* cntF, int n) {
  int i = blockIdx.x * blockDim.x + threadIdx.x;
  if (i < n && mark2[i]) {
    int p = atomicAdd(cntF, 1);
    if (p < NF_CAP) { list[p] = i; fidx[i] = p; }
  }
}

// --- pass 2a: per-bucket degree + per-node frontier match counts (LDS) -------
__global__ __launch_bounds__(1024) void k_degB(const int* __restrict__ gcur,
    const uint2* __restrict__ bktbuf, int cap, const int* __restrict__ fidx,
    float* dinv, int* counts2, int n) {
  __shared__ float acc[1024];
  __shared__ int sfidx[1024];
  __shared__ int scount[1024];
  int t = threadIdx.x, b = blockIdx.x;
  int gbase = b << 10;
  acc[t] = 0.f;
  scount[t] = 0;
  sfidx[t] = (gbase + t < n) ? fidx[gbase + t] : -1;
  __syncthreads();
  int m = min(gcur[b], cap);
  const uint2* base = bktbuf + (size_t)b * cap;
  for (int j = t; j < m; j += 1024) {
    uint2 u = base[j];
    int dl = (int)(u.x & 1023u);
    atomicAdd(&acc[dl], __uint_as_float(u.y));    // LDS fp32 atomic
    if (sfidx[dl] >= 0) atomicAdd(&scount[dl], 1);
  }
  __syncthreads();
  int i = gbase + t;
  if (i < n) {
    dinv[i] = rsqrtf(1.0f + acc[t]);              // +1 = self-loop
    int f = sfidx[t];
    if (f >= 0) counts2[f] = scount[t];           // exclusive owner: no atomic
  }
}

// --- exclusive scan over frontier counts (single block) ----------------------
__global__ __launch_bounds__(1024) void k_scanF(const int* __restrict__ counts2,
                                                const int* __restrict__ cntF,
                                                int* frowptr) {
  __shared__ int sd[1024];
  __shared__ int carry;
  int t = threadIdx.x;
  int nf = min(*cntF, NF_CAP);
  if (t == 0) carry = 0;
  __syncthreads();
  for (int base = 0; base < nf; base += 1024) {
    int i = base + t;
    int v = (i < nf) ? counts2[i] : 0;
    sd[t] = v; __syncthreads();
    for (int off = 1; off < 1024; off <<= 1) {
      int a = (t >= off) ? sd[t - off] : 0;
      __syncthreads();
      sd[t] += a;
      __syncthreads();
    }
    int c = carry;
    if (i < nf) frowptr[i] = c + sd[t] - v;
    __syncthreads();
    if (t == 1023) carry = c + sd[t];
    __syncthreads();
  }
  if (t == 0) frowptr[nf] = carry;
}

// --- pass 2b: scatter matched edges straight into frontier CSR ---------------
__global__ __launch_bounds__(1024) void k_scat2(const int* __restrict__ gcur,
    const uint2* __restrict__ bktbuf, int cap, const int* __restrict__ fidx,
    const int* __restrict__ frowptr, const float* __restrict__ dinv,
    int* fcols, float* fvals, int n) {
  __shared__ int sfidx[1024];
  __shared__ int lcur[1024];
  int t = threadIdx.x, b = blockIdx.x;
  int gbase = b << 10;
  int f = (gbase + t < n) ? fidx[gbase + t] : -1;
  sfidx[t] = f;
  lcur[t] = (f >= 0) ? frowptr[f] : 0;
  __syncthreads();
  int m = min(gcur[b], cap);
  const uint2* base = bktbuf + (size_t)b * cap;
  for (int j = t; j < m; j += 1024) {
    uint2 u = base[j];
    int dl = (int)(u.x & 1023u);
    if (sfidx[dl] >= 0) {
      int pos = atomicAdd(&lcur[dl], 1);          // LDS cursor, no global atomics
      int s = (int)(u.x >> 10);
      fcols[pos] = s;
      fvals[pos] = dinv[s] * __uint_as_float(u.y);   // dst-side dinv in k_h1
    }
  }
}

// --- fused: aggregate x over frontier CSR, then @W1 + b1 ---------------------
__global__ __launch_bounds__(256) void k_h1(const float* __restrict__ x,
    const int* __restrict__ list, const int* __restrict__ cntF,
    const int* __restrict__ frowptr, const int* __restrict__ fcols,
    const float* __restrict__ fvals, const float* __restrict__ dinv,
    const float* __restrict__ W1, const float* __restrict__ b1,
    float* __restrict__ h1) {
  __shared__ float Wl[128 * 64];           // 32 KB
  __shared__ float sag[4][130];
  int t = threadIdx.x;
  for (int p = t; p < 128 * 16; p += 256)
    ((float4*)Wl)[p] = ((const float4*)W1)[p];
  __syncthreads();
  int lane = t & 63, wv = t >> 6;
  int wid = blockIdx.x * 4 + wv;
  int nw = gridDim.x * 4;
  int m = min(*cntF, NF_CAP);
  const float2* x2 = (const float2*)x;
  float bias = b1[lane];
  for (int li = wid; li < m; li += nw) {
    int i = list[li];
    float dv = dinv[i];
    float2 xi = x2[(size_t)i * 64 + lane];
    float2 acc = {0.f, 0.f};
    int beg = frowptr[li], end = frowptr[li + 1];
    for (int p = beg; p < end; ++p) {
      int c = fcols[p];
      float v = fvals[p];
      float2 xc = x2[(size_t)c * 64 + lane];
      acc.x += v * xc.x;
      acc.y += v * xc.y;
    }
    acc.x = dv * (acc.x + dv * xi.x);
    acc.y = dv * (acc.y + dv * xi.y);
    sag[wv][2 * lane] = acc.x;
    sag[wv][2 * lane + 1] = acc.y;
    asm volatile("s_waitcnt lgkmcnt(0)" ::: "memory");
    float o = bias;
#pragma unroll 8
    for (int k = 0; k < 128; ++k)
      o += sag[wv][k] * Wl[k * 64 + lane];
    h1[(size_t)li * 64 + lane] = o;
  }
}

// --- fused: aggregate h1 at 512 sel nodes, @W2 + b2, pairwise max, out -------
__global__ __launch_bounds__(128) void k_h2out(const float* __restrict__ h1,
    const int* __restrict__ sel, const int* __restrict__ fidx,
    const int* __restrict__ frowptr, const int* __restrict__ fcols,
    const float* __restrict__ fvals, const float* __restrict__ dinv,
    const float* __restrict__ W2, const float* __restrict__ b2,
    float* __restrict__ out, int nb) {
  __shared__ float Wl[64 * 64];
  __shared__ float sag[2][64];
  __shared__ float hh[2][64];
  int t = threadIdx.x;
  for (int p = t; p < 64 * 16; p += 128)
    ((float4*)Wl)[p] = ((const float4*)W2)[p];
  __syncthreads();
  int lane = t & 63, wv = t >> 6;
  int b = blockIdx.x;
  if (b >= nb) return;
  int node = sel[2 * b + wv];
  int f = fidx[node];
  float dv = dinv[node];
  float acc = 0.f;
  int beg = frowptr[f], end = frowptr[f + 1];
  for (int p = beg; p < end; ++p) {
    int g = fidx[fcols[p]];
    acc += fvals[p] * h1[(size_t)g * 64 + lane];
  }
  acc = dv * (acc + dv * h1[(size_t)f * 64 + lane]);
  sag[wv][lane] = acc;
  __syncthreads();
  float o = b2[lane];
#pragma unroll 8
  for (int k = 0; k < 64; ++k)
    o += sag[wv][k] * Wl[k * 64 + lane];
  hh[wv][lane] = o;
  __syncthreads();
  if (wv == 0)
    out[(size_t)b * 64 + lane] = fmaxf(hh[0][lane], hh[1][lane]);
}

extern "C" void kernel_launch(void* const* d_in, const int* in_sizes, int n_in,
                              void* d_out, int out_size, void* d_ws, size_t ws_size,
                              hipStream_t stream) {
  const float* x     = (const float*)d_in[0];
  const int*   ei    = (const int*)d_in[1];
  const float* ew    = (const float*)d_in[2];
  const int*   batch = (const int*)d_in[3];
  const float* W1    = (const float*)d_in[4];
  const float* b1    = (const float*)d_in[5];
  const float* W2    = (const float*)d_in[6];
  const float* b2    = (const float*)d_in[7];

  const int E  = in_sizes[2];
  const int N  = in_sizes[3];
  const int B  = out_size / 64;
  const int NC = N / 2;
  const int* srcI = ei;
  const int* dstI = ei + E;

  const int NBKT   = (N + 1023) >> 10;              // 98 for N=100k
  const int CAP    = ((E + NBKT - 1) / NBKT) * 2;   // ~2x expected bucket load
  const int NWORDS = (N + 31) >> 5;

  char* p = (char*)d_ws;
  auto alloc = [&](size_t bytes) -> char* {
    char* r = p;
    p += (bytes + 255) & ~size_t(255);
    return r;
  };
  float* dinv    = (float*)alloc((size_t)N * 4);
  unsigned int* mark1w = (unsigned int*)alloc((size_t)MAXW * 4);
  unsigned char* mark2 = (unsigned char*)alloc(N);
  int*   fidx    = (int*)alloc((size_t)N * 4);
  int*   list    = (int*)alloc((size_t)NF_CAP * 4);
  int*   counts2 = (int*)alloc((size_t)NF_CAP * 4);
  int*   frowptr = (int*)alloc((size_t)(NF_CAP + 1) * 4);
  int*   first   = (int*)alloc((size_t)B * 4);
  int*   sel     = (int*)alloc((size_t)2 * B * 4);
  int*   cnt     = (int*)alloc(256);                // [0]=cntF
  int*   gcur    = (int*)alloc(128 * 4);
  uint2* bktbuf  = (uint2*)alloc((size_t)NBKT * CAP * 8);
  int*   fcols   = (int*)alloc((size_t)E * 4);
  float* fvals   = (float*)alloc((size_t)E * 4);
  float* h1      = (float*)alloc((size_t)NF_CAP * 64 * 4);

  int gN = (N + 255) / 256;
  int gB = (E + CHUNK - 1) / CHUNK;
  int* cntF = cnt;

  k_init<<<gN, 256, 0, stream>>>(mark1w, mark2, fidx, counts2, first, cnt, gcur, N, B);
  k_first<<<(NC + 255) / 256, 256, 0, stream>>>(batch, first, NC);
  k_sel<<<(2 * B + 255) / 256, 256, 0, stream>>>(first, sel, mark1w, mark2, B, NC);
  k_bkt<<<gB, 256, 0, stream>>>(srcI, dstI, ew, mark1w, mark2, gcur, bktbuf, CAP, E, NWORDS);
  k_compact<<<gN, 256, 0, stream>>>(mark2, list, fidx, cntF, N);
  k_degB<<<NBKT, 1024, 0, stream>>>(gcur, bktbuf, CAP, fidx, dinv, counts2, N);
  k_scanF<<<1, 1024, 0, stream>>>(counts2, cntF, frowptr);
  k_scat2<<<NBKT, 1024, 0, stream>>>(gcur, bktbuf, CAP, fidx, frowptr, dinv, fcols, fvals, N);
  k_h1<<<1024, 256, 0, stream>>>(x, list, cntF, frowptr, fcols, fvals, dinv, W1, b1, h1);
  k_h2out<<<B, 128, 0, stream>>>(h1, sel, fidx, frowptr, fcols, fvals, dinv, W2, b2,
                                 (float*)d_out, B);
}